// Round 7
// baseline (456.866 us; speedup 1.0000x reference)
//
#include <hip/hip_runtime.h>
#include <math.h>

// ---------------- problem constants ----------------
#define NBATCH 16
#define NPTS   1024
#define NANG   12
#define NROTS  60
#define EPSV   1e-5f

// ---------------- workspace layout (float offsets) ----------------
// lifetime-aliased; peak extent = 27329536 floats = 109.3 MB (ws >= 384 MiB per fill counters)
#define WB0_OFF   0          // 64*96 bf16 = 3072 floats
#define WB1_OFF   3072       // 128*160 bf16 = 10240 floats (ends 13312)
#define PART0_OFF 13312      // 16*64*64*12  = 786432
#define PART1_OFF 799744     // 16*64*128*12 = 1572864 (ends 2372608)
#define XF_OFF    13312      // 16*512*60 = 491520 (aliases dead PART after feat_mfma)
#define XM_OFF    504832     // 16*512 = 8192
#define OACT_OFF  513024     // 16*512 = 8192 (ends 521216)
#define XCAT_OFF  2372608    // 16*192*12 = 36864
#define XLIN_OFF  2409472    // 16*256*12 = 49152 (ends 2458624)
#define XG_OFF    2458624    // 960*6144 bf16 = 2949120 floats (ends 5407744)
#define BRP_OFF   2458624    // 16*16*128*60 = 1966080 (aliases XG; XG dead by then)
#define HACT_OFF  4424704    // 16*128*60 = 122880
#define AACT_OFF  4547584    // 16*128*60 = 122880 (ends 4670464)
#define FRAW_OFF  5407744    // 3*512*960 = 1474560 (ends 6882304)
#define FEATW_OFF 6882304    // 512*6144 bf16 = 1572864 floats (ends 8455168)
#define XP0_OFF   8455168    // 16*2*12288*32 bf16 = 6291456 floats (ends 14746624)
#define XP1_OFF   14746624   // 16*4*12288*32 bf16 = 12582912 floats (ends 27329536)

// ---------------- output layout (float offsets) ----------------
#define OUT_XOUT 0       // (16,256)   = 4096
#define OUT_ATTN 4096    // (16,60)    = 960
#define OUT_PRED 5056    // (16,60,3,3)= 8640
#define OUT_REST 13696   // (16,60,3)  = 2880

typedef short  bf16x8 __attribute__((ext_vector_type(8)));
typedef float  f32x4  __attribute__((ext_vector_type(4)));

__device__ __forceinline__ unsigned short f2bf_rne(float x){
  unsigned int u = __float_as_uint(x);
  u += 0x7FFFu + ((u >> 16) & 1u);
  return (unsigned short)(u >> 16);
}
__device__ __forceinline__ float bf2f(unsigned short h){
  return __uint_as_float(((unsigned int)h) << 16);
}

__device__ __forceinline__ bf16x8 pack8(const float* f){
  union { unsigned int u[4]; bf16x8 v; } r;
  #pragma unroll
  for (int i = 0; i < 4; i++)
    r.u[i] = __builtin_amdgcn_perm(__float_as_uint(f[2*i+1]),
                                   __float_as_uint(f[2*i]), 0x07060302u);
  return r.v;
}

__device__ __forceinline__ void stage16(const unsigned short* g, unsigned short* l){
  __builtin_amdgcn_global_load_lds((const __attribute__((address_space(1))) void*)g,
                                   (__attribute__((address_space(3))) void*)l, 16, 0, 0);
}

// ---------------- block-wide mean/var helper ----------------
template<int NT>
__device__ __forceinline__ void block_stats(float v, float& m, float& var, float* sbuf){
  constexpr int NW = NT / 64;
  float s = v, s2 = v * v;
  #pragma unroll
  for (int off = 32; off; off >>= 1){
    s  += __shfl_xor(s,  off, 64);
    s2 += __shfl_xor(s2, off, 64);
  }
  const int w = threadIdx.x >> 6;
  if ((threadIdx.x & 63) == 0){ sbuf[w] = s; sbuf[NW + w] = s2; }
  __syncthreads();
  float ts = 0.f, ts2 = 0.f;
  #pragma unroll
  for (int i = 0; i < NW; i++){ ts += sbuf[i]; ts2 += sbuf[NW + i]; }
  m = ts / (float)NT;
  var = ts2 / (float)NT - m * m;
}

// ---------------- pipelined multi-tile transpose: NTILE x (32k x 256n) fp32 -> bf16 [n][k]
// Round-6 post-mortem: one-shot 64B/thread blocks were per-block-LATENCY-bound (2.1 TB/s,
// all pipes idle). Fix: 4 tiles per block, register-prefetch tile t+1's loads under tile t's
// LDS store phase. Single LDS buffer (barriers on both sides already order buf reuse).
// Loads: wave reads 1 KiB contiguous. Stores: wave writes 1 KiB contiguous.
template<int NT, int NTILE>
__device__ __forceinline__ void transpose_multi(
    const float* __restrict__ src, unsigned short* __restrict__ dst,
    unsigned short* tb /* 32*258 shorts */, int t){
  constexpr int QL = 2048 / NT;   // float4 load passes per tile
  constexpr int QS = 1024 / NT;   // 16B store passes per tile
  float4 v[QL];
  #pragma unroll
  for (int q = 0; q < QL; q++){
    const int idx = q * NT + t;
    const int rr = idx >> 6, c4 = (idx & 63) << 2;
    v[q] = *(const float4*)(src + (size_t)rr * 12288 + c4);
  }
  #pragma unroll
  for (int tile = 0; tile < NTILE; tile++){
    // write current regs -> LDS (consumes v)
    #pragma unroll
    for (int q = 0; q < QL; q++){
      const int idx = q * NT + t;
      const int rr = idx >> 6, c4 = (idx & 63) << 2;
      tb[rr * 258 + c4 + 0] = (unsigned short)(__float_as_uint(v[q].x) >> 16);
      tb[rr * 258 + c4 + 1] = (unsigned short)(__float_as_uint(v[q].y) >> 16);
      tb[rr * 258 + c4 + 2] = (unsigned short)(__float_as_uint(v[q].z) >> 16);
      tb[rr * 258 + c4 + 3] = (unsigned short)(__float_as_uint(v[q].w) >> 16);
    }
    // prefetch next tile into regs (latency hides under store phase below)
    if (tile + 1 < NTILE){
      const float* s2 = src + (tile + 1) * 256;
      #pragma unroll
      for (int q = 0; q < QL; q++){
        const int idx = q * NT + t;
        const int rr = idx >> 6, c4 = (idx & 63) << 2;
        v[q] = *(const float4*)(s2 + (size_t)rr * 12288 + c4);
      }
    }
    __syncthreads();
    // store phase: LDS column-gather -> contiguous bf16x8 global stores
    unsigned short* d2 = dst + (size_t)tile * 256 * 32;
    #pragma unroll
    for (int p = 0; p < QS; p++){
      const int gl = p * NT + t;        // 0..1023
      const int col = gl >> 2, kq = gl & 3;
      union { unsigned short s[8]; bf16x8 vv; } ob;
      #pragma unroll
      for (int j = 0; j < 8; j++) ob.s[j] = tb[(kq * 8 + j) * 258 + col];
      *(bf16x8*)(d2 + (size_t)col * 32 + kq * 8) = ob.vv;
    }
    __syncthreads();
  }
}

// ---------------- prep_a: transpose feats0 (4-tile pipelined) + pointnet weight prep -----
// blocks [0,384): feats0 -> Xp0 (4 tiles each); [384,408): wb0; [408,488): wb1
template<int C>
__device__ __forceinline__ void prep_wb_body(int idx, const float* __restrict__ W,
                                             unsigned short* __restrict__ Wb){
  constexpr int KPAD = C + 32;
  if (idx >= C * KPAD) return;
  const int o = idx / KPAD, k = idx % KPAD;
  float v = 0.f;
  if (k < C)          v = W[(size_t)o * (C + 3) + 3 + k];
  else if (k < C + 3) v = W[(size_t)o * (C + 3) + (k - C)];
  Wb[idx] = f2bf_rne(v);
}

__global__ __launch_bounds__(256) void prep_a(
    const float* __restrict__ feats0, unsigned short* __restrict__ xp0,
    const float* __restrict__ W0, const float* __restrict__ W1,
    unsigned short* __restrict__ wb0, unsigned short* __restrict__ wb1){
  __shared__ unsigned short tr[32 * 258];
  const int blk = blockIdx.x;
  if (blk < 384){
    const int tb = blk * 4;                   // 4 consecutive tiles, same kt (48%4==0)
    const int nt = tb % 48, kt = tb / 48;     // kt = b*2 + ks (0..31)
    transpose_multi<256, 4>(feats0 + (size_t)kt * 32 * 12288 + nt * 256,
                            xp0 + ((size_t)kt * 12288 + nt * 256) * 32,
                            tr, threadIdx.x);
  } else if (blk < 408){
    prep_wb_body<64>((blk - 384) * 256 + threadIdx.x, W0, wb0);
  } else {
    prep_wb_body<128>((blk - 408) * 256 + threadIdx.x, W1, wb1);
  }
}

// ---------------- pointnet GEMM: pre-packed bf16 B, 16B/lane fragment loads --------------
// 512-thread blocks, 8 waves = 2 o-halves x 4 n-groups. Each wave: (C/2) o x 48 n.
#define SROW 196
template<int C>
__device__ __forceinline__ void pn_body(
    int nchunk, int b,
    const float* __restrict__ xyz, const unsigned short* __restrict__ Xp,
    const unsigned short* __restrict__ Wb, float* __restrict__ part,
    float* yb /* 2 * 16*SROW floats LDS */){
  constexpr int KPAD = C + 32;
  constexpr int NFK  = C / 32;
  constexpr int MTH  = C / 32;      // m-tiles per o-half
  const int tid  = threadIdx.x;     // 0..511
  const int lane = tid & 63, w = tid >> 6;
  const int wo = w >> 2, wn = w & 3;
  const int g = lane >> 4, l16 = lane & 15;
  const int o_off = wo * (C / 2);
  const int nbase = nchunk * 192;

  int nn[3], pp[3];
  #pragma unroll
  for (int t = 0; t < 3; t++){
    nn[t] = wn * 48 + t * 16 + l16;
    pp[t] = (nbase + nn[t]) / 12;
  }

  f32x4 acc[MTH][3];
  #pragma unroll
  for (int m = 0; m < MTH; m++)
    #pragma unroll
    for (int t = 0; t < 3; t++)
      acc[m][t] = (f32x4){0.f, 0.f, 0.f, 0.f};

  const unsigned short* xbase = Xp + (size_t)b * NFK * 12288 * 32 + g * 8;
  bf16x8 Bf[NFK][3];
  #pragma unroll
  for (int ks = 0; ks < NFK; ks++)
    #pragma unroll
    for (int t = 0; t < 3; t++)
      Bf[ks][t] = *(const bf16x8*)(xbase + ((size_t)ks * 12288 + nbase + nn[t]) * 32);

  #pragma unroll
  for (int ks = 0; ks < NFK; ks++){
    const int kb = ks * 32;
    #pragma unroll
    for (int m = 0; m < MTH; m++){
      const bf16x8 Af = *(const bf16x8*)(Wb + (size_t)(o_off + m * 16 + l16) * KPAD + kb + g * 8);
      #pragma unroll
      for (int t = 0; t < 3; t++)
        acc[m][t] = __builtin_amdgcn_mfma_f32_16x16x32_bf16(Af, Bf[ks][t], acc[m][t], 0, 0, 0);
    }
  }

  { // xyz K-step
    const int kb = C;
    bf16x8 Bf2[3];
    #pragma unroll
    for (int t = 0; t < 3; t++){
      float f[8];
      #pragma unroll
      for (int j = 0; j < 8; j++) f[j] = 0.f;
      if (g == 0){
        #pragma unroll
        for (int j = 0; j < 3; j++)
          f[j] = xyz[(size_t)(b * 3 + j) * NPTS + pp[t]];
      }
      Bf2[t] = pack8(f);
    }
    #pragma unroll
    for (int m = 0; m < MTH; m++){
      const bf16x8 Af = *(const bf16x8*)(Wb + (size_t)(o_off + m * 16 + l16) * KPAD + kb + g * 8);
      #pragma unroll
      for (int t = 0; t < 3; t++)
        acc[m][t] = __builtin_amdgcn_mfma_f32_16x16x32_bf16(Af, Bf2[t], acc[m][t], 0, 0, 0);
    }
  }

  float* myb = yb + wo * (16 * SROW);
  #pragma unroll
  for (int m = 0; m < MTH; m++){
    __syncthreads();
    #pragma unroll
    for (int t = 0; t < 3; t++)
      #pragma unroll
      for (int r = 0; r < 4; r++)
        myb[(g * 4 + r) * SROW + nn[t]] = acc[m][t][r];
    __syncthreads();
    const int lt = tid & 255;
    if (lt < 192){
      const int o_l = lt / 12, a = lt % 12;
      float mx = -3.4e38f;
      #pragma unroll
      for (int pl = 0; pl < 16; pl++)
        mx = fmaxf(mx, myb[o_l * SROW + pl * 12 + a]);
      part[((size_t)(b * 64 + nchunk) * C + o_off + m * 16 + o_l) * 12 + a] = mx;
    }
  }
}

// ---------------- prep_b: feats1 4-tile transpose || pn0 || featw x8-vec (512 thr) -------
// blocks [0,768): feats1->Xp1 (4 tiles each); [768,1792): pn0; [1792,2176): featw
__global__ __launch_bounds__(512, 4) void prep_b(
    const float* __restrict__ feats1, unsigned short* __restrict__ xp1,
    const float* __restrict__ xyz0, const unsigned short* __restrict__ xp0,
    const unsigned short* __restrict__ wb0, float* __restrict__ part0,
    const float* __restrict__ FW, unsigned short* __restrict__ fw2){
  __shared__ float smem[2 * 16 * SROW];   // 25088 B (transpose uses 16512 B of it)
  const int blk = blockIdx.x;
  if (blk < 768){
    const int tb = blk * 4;                   // 4 consecutive tiles, same kt
    const int nt = tb % 48, kt = tb / 48;     // kt = b*4 + ks (0..63)
    transpose_multi<512, 4>(feats1 + (size_t)kt * 32 * 12288 + nt * 256,
                            xp1 + ((size_t)kt * 12288 + nt * 256) * 32,
                            (unsigned short*)smem, threadIdx.x);
  } else if (blk < 1792){
    const int blk2 = blk - 768;
    pn_body<64>(blk2 & 63, blk2 >> 6, xyz0, xp0, wb0, part0, smem);
  } else {
    // featw hi/lo, 8 elems/thread: float4 x2 loads, bf16x8 stores
    const int base = ((blk - 1792) * 512 + threadIdx.x) * 8;   // < 512*3072
    const int o = base / 3072, k = base % 3072;
    const float4 va = *(const float4*)(FW + base);
    const float4 vb = *(const float4*)(FW + base + 4);
    const float xs[8] = {va.x, va.y, va.z, va.w, vb.x, vb.y, vb.z, vb.w};
    union { unsigned short s[8]; bf16x8 v; } hi, lo;
    #pragma unroll
    for (int j = 0; j < 8; j++){
      hi.s[j] = f2bf_rne(xs[j]);
      lo.s[j] = f2bf_rne(xs[j] - bf2f(hi.s[j]));
    }
    *(bf16x8*)(fw2 + (size_t)o * 6144 + k) = hi.v;
    *(bf16x8*)(fw2 + (size_t)o * 6144 + 3072 + k) = lo.v;
  }
}

// ---------------- pn1: heavy pointnet alone ----------------
__global__ __launch_bounds__(512, 4) void pn1(
    const float* __restrict__ xyz1, const unsigned short* __restrict__ xp1,
    const unsigned short* __restrict__ wb1, float* __restrict__ part1){
  __shared__ float yb[2 * 16 * SROW];
  pn_body<128>(blockIdx.x, blockIdx.y, xyz1, xp1, wb1, part1, yb);
}

// ---------------- reduce chunks + bias + BN + relu -> xcat (16,192,12) ----------------
__global__ void pn_reduce_bn(const float* __restrict__ part0, const float* __restrict__ part1,
    const float* __restrict__ b0, const float* __restrict__ g0, const float* __restrict__ bb0,
    const float* __restrict__ b1, const float* __restrict__ g1, const float* __restrict__ bb1,
    float* __restrict__ xcat){
  const int ch = blockIdx.x, t = threadIdx.x;
  const int b = t / 12, a = t % 12;
  const float* part; const float *bias, *g, *bb; int o, Cl;
  if (ch < 64){ part = part0; bias = b0; g = g0; bb = bb0; o = ch;      Cl = 64;  }
  else        { part = part1; bias = b1; g = g1; bb = bb1; o = ch - 64; Cl = 128; }
  const float* pp = part + ((size_t)(b * 64) * Cl + o) * 12 + a;
  const size_t kstride = (size_t)Cl * 12;
  float v = pp[0];
  for (int k = 1; k < 64; k++) v = fmaxf(v, pp[(size_t)k * kstride]);
  v += bias[o];
  __shared__ float sbuf[8];
  float m, var;
  block_stats<192>(v, m, var, sbuf);
  float xn = (v - m) * rsqrtf(var + EPSV) * g[o] + bb[o];
  xcat[((size_t)b * 192 + ch) * 12 + a] = fmaxf(xn, 0.f);
}

// ---------------- lin layer + BN (no relu) -> xlin (16,256,12) ----------------
__global__ void lin_bn(const float* __restrict__ xcat, const float* __restrict__ W,
    const float* __restrict__ bias, const float* __restrict__ g, const float* __restrict__ bb,
    float* __restrict__ xlin){
  const int o = blockIdx.x, t = threadIdx.x;
  const int b = t / 12, a = t % 12;
  const float* xr = xcat + (size_t)b * 2304 + a;
  const float* wr = W + (size_t)o * 192;
  float v = bias[o];
  for (int c = 0; c < 192; c++) v = fmaf(wr[c], xr[(size_t)c * 12], v);
  __shared__ float sbuf[8];
  float m, var;
  block_stats<192>(v, m, var, sbuf);
  xlin[((size_t)b * 256 + o) * 12 + a] = (v - m) * rsqrtf(var + EPSV) * g[o] + bb[o];
}

// ---------------- prep: gathered activations Xg [n=960][hi(3072) | lo(3072)] bf16 --------
__global__ void prep_xg(const float* __restrict__ xlin, const int* __restrict__ trace,
                        unsigned short* __restrict__ Xg){
  const int n = blockIdx.x;           // 0..959
  const int b = n / 60, r = n % 60;
  unsigned short* row = Xg + (size_t)n * 6144;
  __shared__ int ta[12];
  if (threadIdx.x < 12) ta[threadIdx.x] = trace[threadIdx.x * 60 + r];
  __syncthreads();
  for (int i = threadIdx.x; i < 3072; i += 256){
    const int c = i / 12, a = i % 12;
    const float x = xlin[((size_t)b * 256 + c) * 12 + ta[a]];
    const unsigned short hi = f2bf_rne(x);
    const unsigned short lo = f2bf_rne(x - bf2f(hi));
    row[i] = hi;
    row[3072 + i] = lo;
  }
}

// ---------------- feat GEMM: LDS-staged MFMA, XOR-swizzled chunks ----------------
__global__ __launch_bounds__(256) void feat_mfma(
    const unsigned short* __restrict__ Wb2, const unsigned short* __restrict__ Xg,
    float* __restrict__ fraw){
  const int nblk = blockIdx.x, mblk = blockIdx.y, seg = blockIdx.z;
  const int tid = threadIdx.x;
  const int lane = tid & 63, wave = tid >> 6;
  const int g = lane >> 4, l16 = lane & 15;
  const int kA = (seg == 1) ? 3072 : 0;
  const int kB = (seg == 2) ? 3072 : 0;
  const int sw = l16 & 7;
  const int wm = wave >> 1, wn = wave & 1;

  __shared__ unsigned short As[2][64 * 64];
  __shared__ unsigned short Bs[2][64 * 64];

  int rowj[2], colj[2], ldsoff[2];
  #pragma unroll
  for (int j = 0; j < 2; j++){
    const int idx = j * 256 + wave * 64 + lane;
    rowj[j]   = idx >> 3;
    colj[j]   = ((idx & 7) ^ (rowj[j] & 7)) * 8;
    ldsoff[j] = (j * 256 + wave * 64) * 8;
  }
  const unsigned short* Agb = Wb2 + (size_t)mblk * 64 * 6144 + kA;
  const unsigned short* Bgb = Xg  + (size_t)nblk * 64 * 6144 + kB;

  f32x4 acc[2][2];
  #pragma unroll
  for (int i = 0; i < 2; i++)
    #pragma unroll
    for (int j = 0; j < 2; j++)
      acc[i][j] = (f32x4){0.f, 0.f, 0.f, 0.f};

  #pragma unroll
  for (int j = 0; j < 2; j++){
    stage16(Agb + (size_t)rowj[j] * 6144 + colj[j], &As[0][ldsoff[j]]);
    stage16(Bgb + (size_t)rowj[j] * 6144 + colj[j], &Bs[0][ldsoff[j]]);
  }
  __syncthreads();

  for (int kc = 0; kc < 3072; kc += 64){
    const int buf = (kc >> 6) & 1;
    if (kc + 64 < 3072){
      const int kn = kc + 64;
      #pragma unroll
      for (int j = 0; j < 2; j++){
        stage16(Agb + (size_t)rowj[j] * 6144 + kn + colj[j], &As[buf ^ 1][ldsoff[j]]);
        stage16(Bgb + (size_t)rowj[j] * 6144 + kn + colj[j], &Bs[buf ^ 1][ldsoff[j]]);
      }
    }
    #pragma unroll
    for (int kc2 = 0; kc2 < 64; kc2 += 32){
      const int c0 = kc2 >> 3;
      bf16x8 af[2], bfr[2];
      #pragma unroll
      for (int i = 0; i < 2; i++)
        af[i]  = *(const bf16x8*)&As[buf][(wm * 32 + i * 16 + l16) * 64 + ((c0 + g) ^ sw) * 8];
      #pragma unroll
      for (int i = 0; i < 2; i++)
        bfr[i] = *(const bf16x8*)&Bs[buf][(wn * 32 + i * 16 + l16) * 64 + ((c0 + g) ^ sw) * 8];
      #pragma unroll
      for (int i = 0; i < 2; i++)
        #pragma unroll
        for (int j = 0; j < 2; j++)
          acc[i][j] = __builtin_amdgcn_mfma_f32_16x16x32_bf16(af[i], bfr[j], acc[i][j], 0, 0, 0);
    }
    __syncthreads();
  }

  float* base = fraw + (size_t)seg * (512 * 960);
  #pragma unroll
  for (int i = 0; i < 2; i++)
    #pragma unroll
    for (int j = 0; j < 2; j++){
      const int n = nblk * 64 + wn * 32 + j * 16 + l16;
      #pragma unroll
      for (int q = 0; q < 4; q++){
        const int m = mblk * 64 + wm * 32 + i * 16 + g * 4 + q;
        base[(size_t)m * 960 + n] = acc[i][j][q];
      }
    }
}

// ---------------- feat: sum 3 segs + bias + BN + relu + per-b max over r ----------------
__global__ void feat_bn(const float* __restrict__ fraw, const float* __restrict__ bias,
    const float* __restrict__ g, const float* __restrict__ bb,
    float* __restrict__ xf, float* __restrict__ xm){
  const int o = blockIdx.x, t = threadIdx.x;
  const int b = t / 60, r = t % 60;
  const size_t SS = (size_t)512 * 960;
  const size_t in = (size_t)o * 960 + t;
  float v = fraw[in] + fraw[SS + in] + fraw[2 * SS + in] + bias[o];
  __shared__ float sbuf[32];
  float m, var;
  block_stats<960>(v, m, var, sbuf);
  const float xn = fmaxf((v - m) * rsqrtf(var + EPSV) * g[o] + bb[o], 0.f);
  xf[((size_t)b * 512 + o) * 60 + r] = xn;
  __shared__ float red[960];
  red[t] = xn;
  __syncthreads();
  if (r == 0){
    float mx = red[t];
    for (int k = 1; k < 60; k++) mx = fmaxf(mx, red[t + k]);
    xm[(size_t)b * 512 + o] = mx;
  }
}

// ---------------- branch GEMMs fused (reg_W1 & att_W1), K split 8; + out_head1 -----------
__global__ __launch_bounds__(256) void brgemm_oh1(const float* __restrict__ xf,
    const float* __restrict__ Wr, const float* __restrict__ Wa,
    float* __restrict__ brp,
    const float* __restrict__ xm, const float* __restrict__ oW1,
    const float* __restrict__ ob1, const float* __restrict__ og,
    const float* __restrict__ obb, float* __restrict__ o_act){
  const int z = blockIdx.z;
  if (z == 16){
    const int q = blockIdx.y * 4 + blockIdx.x;
    if (q >= 32) return;
    const int t = threadIdx.x;
    const int b = t & 15, j = t >> 4;
    const int oc = q * 16 + j;
    float acc = ob1[oc];
    const float* wr = oW1 + (size_t)oc * 512;
    const float* xr = xm + (size_t)b * 512;
    for (int c = 0; c < 512; c++) acc = fmaf(wr[c], xr[c], acc);
    float s = acc, s2 = acc * acc;
    #pragma unroll
    for (int off = 8; off; off >>= 1){
      s  += __shfl_xor(s,  off, 16);
      s2 += __shfl_xor(s2, off, 16);
    }
    const float m = s * (1.f / 16.f);
    const float var = s2 * (1.f / 16.f) - m * m;
    o_act[(size_t)b * 512 + oc] = fmaxf((acc - m) * rsqrtf(var + EPSV) * og[oc] + obb[oc], 0.f);
    return;
  }
  const int og_ = blockIdx.x, b = blockIdx.y;
  const int br = z >> 3, ks = z & 7;
  const float* W = br ? Wa : Wr;
  const int lane = threadIdx.x & 63, wave = threadIdx.x >> 6;
  const int obase = og_ * 32 + wave * 8;
  const int rr = lane < 60 ? lane : 0;
  const float* xb = xf + ((size_t)b * 512 + ks * 64) * 60 + rr;
  const float* wr = W + (size_t)obase * 512 + ks * 64;

  float acc[8];
  #pragma unroll
  for (int i = 0; i < 8; i++) acc[i] = 0.f;

  float cur[4], nxt[4];
  #pragma unroll
  for (int j = 0; j < 4; j++) cur[j] = xb[(size_t)j * 60];

  for (int c0 = 0; c0 < 64; c0 += 4){
    #pragma unroll
    for (int j = 0; j < 4; j++){
      int cc = c0 + 4 + j; if (cc > 63) cc = 63;
      nxt[j] = xb[(size_t)cc * 60];
    }
    #pragma unroll
    for (int j = 0; j < 4; j++)
      #pragma unroll
      for (int i = 0; i < 8; i++)
        acc[i] = fmaf(wr[(size_t)i * 512 + c0 + j], cur[j], acc[i]);
    #pragma unroll
    for (int j = 0; j < 4; j++) cur[j] = nxt[j];
  }

  if (lane < 60){
    #pragma unroll
    for (int i = 0; i < 8; i++)
      brp[(((size_t)z * NBATCH + b) * 128 + obase + i) * 60 + lane] = acc[i];
  }
}

// ---------------- branch: sum 8 K-slabs + bias + BN + relu ----------------
__global__ void br_bn(const float* __restrict__ brp,
    const float* __restrict__ biasR, const float* __restrict__ gR, const float* __restrict__ bbR,
    const float* __restrict__ biasA, const float* __restrict__ gA, const float* __restrict__ bbA,
    float* __restrict__ hact, float* __restrict__ aact){
  const int o = blockIdx.x, br = blockIdx.y, t = threadIdx.x;
  const int b = t / 60, r = t % 60;
  const float* bias = br ? biasA : biasR;
  const float* g    = br ? gA    : gR;
  const float* bb   = br ? bbA   : bbR;
  float v = bias[o];
  #pragma unroll
  for (int ks = 0; ks < 8; ks++)
    v += brp[((((size_t)br * 8 + ks) * NBATCH + b) * 128 + o) * 60 + r];
  __shared__ float sbuf[32];
  float m, var;
  block_stats<960>(v, m, var, sbuf);
  float* outp = br ? aact : hact;
  outp[((size_t)b * 128 + o) * 60 + r] =
      fmaxf((v - m) * rsqrtf(var + EPSV) * g[o] + bb[o], 0.f);
}

// ---------------- heads: reg2_geom (y=0), att2_softmax (y=1), out_head2 (y=2) ------------
__global__ void heads(
    const float* __restrict__ h, const float* __restrict__ rW2,
    const float* __restrict__ rb2, const float* __restrict__ anchors,
    const float* __restrict__ a, const float* __restrict__ aW2, const float* __restrict__ ab2,
    const float* __restrict__ o_act, const float* __restrict__ oW2,
    const float* __restrict__ ob2, float* __restrict__ out){
  const int b = blockIdx.x, sel = blockIdx.y, t = threadIdx.x;
  if (sel == 0){
    if (t >= 64) return;
    const int r = t < 60 ? t : 59;
    float res[7];
    #pragma unroll
    for (int j = 0; j < 7; j++) res[j] = rb2[j];
    for (int c = 0; c < 128; c++){
      const float hv = h[((size_t)b * 128 + c) * 60 + r];
      #pragma unroll
      for (int j = 0; j < 7; j++) res[j] = fmaf(rW2[j * 128 + c], hv, res[j]);
    }
    if (t >= 60) return;
    const float n = sqrtf(res[0]*res[0] + res[1]*res[1] + res[2]*res[2]);
    const float invn = 1.f / n;
    const float Nv = (1.f / (1.f + expf(-res[3])) - 0.5f) * 3.14159265358979323846f / 5.f;
    const float v0 = res[0]*invn*Nv, v1 = res[1]*invn*Nv, v2 = res[2]*invn*Nv;
    const float th = sqrtf(v0*v0 + v1*v1 + v2*v2);
    const float invt = th < 1e-8f ? 1.f : 1.f / th;
    const float k0 = v0*invt, k1 = v1*invt, k2 = v2*invt;
    const float s = sinf(th), cc = 1.f - cosf(th);
    const float K[9] = {0.f, -k2, k1,  k2, 0.f, -k0,  -k1, k0, 0.f};
    float K2[9];
    #pragma unroll
    for (int ii = 0; ii < 3; ii++)
      #pragma unroll
      for (int jj = 0; jj < 3; jj++)
        K2[ii*3+jj] = K[ii*3+0]*K[0*3+jj] + K[ii*3+1]*K[1*3+jj] + K[ii*3+2]*K[2*3+jj];
    float R[9];
    #pragma unroll
    for (int ii = 0; ii < 3; ii++)
      #pragma unroll
      for (int jj = 0; jj < 3; jj++)
        R[ii*3+jj] = (ii == jj ? 1.f : 0.f) + s * K[ii*3+jj] + cc * K2[ii*3+jj];
    const float* A = anchors + (size_t)t * 9;
    #pragma unroll
    for (int ii = 0; ii < 3; ii++)
      #pragma unroll
      for (int kk = 0; kk < 3; kk++){
        const float pv = A[ii*3+0]*R[0*3+kk] + A[ii*3+1]*R[1*3+kk] + A[ii*3+2]*R[2*3+kk];
        out[OUT_PRED + ((size_t)b * 60 + t) * 9 + ii * 3 + kk] = pv;
      }
    #pragma unroll
    for (int k = 0; k < 3; k++)
      out[OUT_REST + ((size_t)b * 60 + t) * 3 + k] = res[4 + k];
  } else if (sel == 1){
    if (t >= 64) return;
    const int r = t < 60 ? t : 59;
    float acc = ab2[0];
    for (int c = 0; c < 128; c++)
      acc = fmaf(aW2[c], a[((size_t)b * 128 + c) * 60 + r], acc);
    const float l = t < 60 ? acc : -INFINITY;
    float mx = l;
    #pragma unroll
    for (int off = 32; off; off >>= 1) mx = fmaxf(mx, __shfl_xor(mx, off, 64));
    const float e = t < 60 ? expf(l - mx) : 0.f;
    float ssum = e;
    #pragma unroll
    for (int off = 32; off; off >>= 1) ssum += __shfl_xor(ssum, off, 64);
    if (t < 60) out[OUT_ATTN + (size_t)b * 60 + t] = e / ssum;
  } else {
    const float* wr = oW2 + (size_t)t * 512;
    const float* xr = o_act + (size_t)b * 512;
    float acc = ob2[t];
    for (int c = 0; c < 512; c++) acc = fmaf(wr[c], xr[c], acc);
    out[OUT_XOUT + (size_t)b * 256 + t] = acc;
  }
}

// ---------------- launch ----------------
extern "C" void kernel_launch(void* const* d_in, const int* in_sizes, int n_in,
                              void* d_out, int out_size, void* d_ws, size_t ws_size,
                              hipStream_t stream){
  const float* xyz0    = (const float*)d_in[0];
  const float* feats0  = (const float*)d_in[1];
  const float* xyz1    = (const float*)d_in[2];
  const float* feats1  = (const float*)d_in[3];
  const int*   trace   = (const int*)  d_in[4];
  const float* anchors = (const float*)d_in[5];
  const float* pn0_W  = (const float*)d_in[6];
  const float* pn0_b  = (const float*)d_in[7];
  const float* pn0_g  = (const float*)d_in[8];
  const float* pn0_bb = (const float*)d_in[9];
  const float* pn1_W  = (const float*)d_in[10];
  const float* pn1_b  = (const float*)d_in[11];
  const float* pn1_g  = (const float*)d_in[12];
  const float* pn1_bb = (const float*)d_in[13];
  const float* lin_W  = (const float*)d_in[14];
  const float* lin_b  = (const float*)d_in[15];
  const float* lin_g  = (const float*)d_in[16];
  const float* lin_bb = (const float*)d_in[17];
  const float* feat_W  = (const float*)d_in[18];
  const float* feat_b  = (const float*)d_in[19];
  const float* feat_g  = (const float*)d_in[20];
  const float* feat_bb = (const float*)d_in[21];
  const float* att_W1 = (const float*)d_in[22];
  const float* att_b1 = (const float*)d_in[23];
  const float* att_g  = (const float*)d_in[24];
  const float* att_bb = (const float*)d_in[25];
  const float* att_W2 = (const float*)d_in[26];
  const float* att_b2 = (const float*)d_in[27];
  const float* reg_W1 = (const float*)d_in[28];
  const float* reg_b1 = (const float*)d_in[29];
  const float* reg_g  = (const float*)d_in[30];
  const float* reg_bb = (const float*)d_in[31];
  const float* reg_W2 = (const float*)d_in[32];
  const float* reg_b2 = (const float*)d_in[33];
  const float* out_W1 = (const float*)d_in[34];
  const float* out_b1 = (const float*)d_in[35];
  const float* out_g  = (const float*)d_in[36];
  const float* out_bb = (const float*)d_in[37];
  const float* out_W2 = (const float*)d_in[38];
  const float* out_b2 = (const float*)d_in[39];

  float* ws  = (float*)d_ws;
  float* out = (float*)d_out;
  unsigned short* wb0 = (unsigned short*)(ws + WB0_OFF);
  unsigned short* wb1 = (unsigned short*)(ws + WB1_OFF);
  unsigned short* fw  = (unsigned short*)(ws + FEATW_OFF);
  unsigned short* xg  = (unsigned short*)(ws + XG_OFF);
  unsigned short* xp0 = (unsigned short*)(ws + XP0_OFF);
  unsigned short* xp1 = (unsigned short*)(ws + XP1_OFF);

  // 1. transpose feats0 (pipelined) + pointnet weight prep
  prep_a<<<488, 256, 0, stream>>>(feats0, xp0, pn0_W, pn1_W, wb0, wb1);

  // 2. transpose feats1 (pipelined) || pn0 || featw (vectorized)
  prep_b<<<2176, 512, 0, stream>>>(feats1, xp1, xyz0, xp0, wb0, ws + PART0_OFF, feat_W, fw);

  // 3. heavy pointnet
  pn1<<<dim3(64, 16), 512, 0, stream>>>(xyz1, xp1, wb1, ws + PART1_OFF);

  // 4. reduce + BN + relu -> concat
  pn_reduce_bn<<<192, 192, 0, stream>>>(ws + PART0_OFF, ws + PART1_OFF,
      pn0_b, pn0_g, pn0_bb, pn1_b, pn1_g, pn1_bb, ws + XCAT_OFF);

  // 5. lin + BN
  lin_bn<<<256, 192, 0, stream>>>(ws + XCAT_OFF, lin_W, lin_b, lin_g, lin_bb, ws + XLIN_OFF);

  // 6. gathered activations hi/lo
  prep_xg<<<960, 256, 0, stream>>>(ws + XLIN_OFF, trace, xg);

  // 7. feat GEMM via LDS-staged MFMA (3 segments)
  feat_mfma<<<dim3(15, 8, 3), 256, 0, stream>>>(fw, xg, ws + FRAW_OFF);

  // 8. sum segs + BN + relu + per-b max
  feat_bn<<<512, 960, 0, stream>>>(ws + FRAW_OFF, feat_b, feat_g, feat_bb,
                                   ws + XF_OFF, ws + XM_OFF);

  // 9. branch GEMMs (K split 8) + out_head1 merged as z=16
  brgemm_oh1<<<dim3(4, 16, 17), 256, 0, stream>>>(ws + XF_OFF, reg_W1, att_W1, ws + BRP_OFF,
      ws + XM_OFF, out_W1, out_b1, out_g, out_bb, ws + OACT_OFF);

  // 10. branch BN
  br_bn<<<dim3(128, 2), 960, 0, stream>>>(ws + BRP_OFF,
      reg_b1, reg_g, reg_bb, att_b1, att_g, att_bb,
      ws + HACT_OFF, ws + AACT_OFF);

  // 11. heads
  heads<<<dim3(16, 3), 256, 0, stream>>>(ws + HACT_OFF, reg_W2, reg_b2, anchors,
      ws + AACT_OFF, att_W2, att_b2, ws + OACT_OFF, out_W2, out_b2, out);
}

// Round 9
// 437.863 us; speedup vs baseline: 1.0434x; 1.0434x over previous
//
#include <hip/hip_runtime.h>
#include <math.h>

// ---------------- problem constants ----------------
#define NBATCH 16
#define NPTS   1024
#define NANG   12
#define NROTS  60
#define EPSV   1e-5f

// ---------------- workspace layout (float offsets) ----------------
// lifetime-aliased; peak extent = 8455168 floats = 33.8 MB
#define WB0_OFF   0          // 64*96 bf16 = 3072 floats
#define WB1_OFF   3072       // 128*160 bf16 = 10240 floats (ends 13312)
#define PART0_OFF 13312      // 16*64*64*12  = 786432
#define PART1_OFF 799744     // 16*64*128*12 = 1572864 (ends 2372608)
#define XF_OFF    13312      // 16*512*60 = 491520 (aliases dead PART after feat_mfma)
#define XM_OFF    504832     // 16*512 = 8192
#define OACT_OFF  513024     // 16*512 = 8192 (ends 521216)
#define XCAT_OFF  2372608    // 16*192*12 = 36864
#define XLIN_OFF  2409472    // 16*256*12 = 49152 (ends 2458624)
#define XG_OFF    2458624    // 960*6144 bf16 = 2949120 floats (ends 5407744)
#define BRP_OFF   2458624    // 16*16*128*60 = 1966080 (aliases XG; XG dead by then)
#define HACT_OFF  4424704    // 16*128*60 = 122880
#define AACT_OFF  4547584    // 16*128*60 = 122880 (ends 4670464)
#define FRAW_OFF  5407744    // 3*512*960 = 1474560 (ends 6882304)
#define FEATW_OFF 6882304    // 512*6144 bf16 = 1572864 floats (ends 8455168)

// ---------------- output layout (float offsets) ----------------
#define OUT_XOUT 0       // (16,256)   = 4096
#define OUT_ATTN 4096    // (16,60)    = 960
#define OUT_PRED 5056    // (16,60,3,3)= 8640
#define OUT_REST 13696   // (16,60,3)  = 2880

typedef short  bf16x8 __attribute__((ext_vector_type(8)));
typedef float  f32x4  __attribute__((ext_vector_type(4)));

__device__ __forceinline__ unsigned short f2bf_rne(float x){
  unsigned int u = __float_as_uint(x);
  u += 0x7FFFu + ((u >> 16) & 1u);
  return (unsigned short)(u >> 16);
}
__device__ __forceinline__ float bf2f(unsigned short h){
  return __uint_as_float(((unsigned int)h) << 16);
}

__device__ __forceinline__ bf16x8 pack8(const float* f){
  union { unsigned int u[4]; bf16x8 v; } r;
  #pragma unroll
  for (int i = 0; i < 4; i++)
    r.u[i] = __builtin_amdgcn_perm(__float_as_uint(f[2*i+1]),
                                   __float_as_uint(f[2*i]), 0x07060302u);
  return r.v;
}

__device__ __forceinline__ void stage16(const unsigned short* g, unsigned short* l){
  __builtin_amdgcn_global_load_lds((const __attribute__((address_space(1))) void*)g,
                                   (__attribute__((address_space(3))) void*)l, 16, 0, 0);
}

// ---------------- block-wide mean/var helper ----------------
template<int NT>
__device__ __forceinline__ void block_stats(float v, float& m, float& var, float* sbuf){
  constexpr int NW = NT / 64;
  float s = v, s2 = v * v;
  #pragma unroll
  for (int off = 32; off; off >>= 1){
    s  += __shfl_xor(s,  off, 64);
    s2 += __shfl_xor(s2, off, 64);
  }
  const int w = threadIdx.x >> 6;
  if ((threadIdx.x & 63) == 0){ sbuf[w] = s; sbuf[NW + w] = s2; }
  __syncthreads();
  float ts = 0.f, ts2 = 0.f;
  #pragma unroll
  for (int i = 0; i < NW; i++){ ts += sbuf[i]; ts2 += sbuf[NW + i]; }
  m = ts / (float)NT;
  var = ts2 / (float)NT - m * m;
}

// ---------------- prep_all: wb0 + wb1 + featw (vectorized), ONE launch -------------------
// blocks [0,24): wb0; [24,104): wb1; [104,872): featw hi/lo, 8 elems/thread
template<int C>
__device__ __forceinline__ void prep_wb_body(int idx, const float* __restrict__ W,
                                             unsigned short* __restrict__ Wb){
  constexpr int KPAD = C + 32;
  if (idx >= C * KPAD) return;
  const int o = idx / KPAD, k = idx % KPAD;
  float v = 0.f;
  if (k < C)          v = W[(size_t)o * (C + 3) + 3 + k];
  else if (k < C + 3) v = W[(size_t)o * (C + 3) + (k - C)];
  Wb[idx] = f2bf_rne(v);
}

__global__ __launch_bounds__(256) void prep_all(
    const float* __restrict__ W0, const float* __restrict__ W1,
    const float* __restrict__ FW,
    unsigned short* __restrict__ wb0, unsigned short* __restrict__ wb1,
    unsigned short* __restrict__ fw2){
  const int blk = blockIdx.x;
  if (blk < 24){
    prep_wb_body<64>(blk * 256 + threadIdx.x, W0, wb0);
  } else if (blk < 104){
    prep_wb_body<128>((blk - 24) * 256 + threadIdx.x, W1, wb1);
  } else {
    // featw hi/lo, 8 elems/thread: float4 x2 loads, bf16x8 stores (3072%8==0 -> in-row)
    const int base = ((blk - 104) * 256 + threadIdx.x) * 8;   // < 512*3072 exactly
    const int o = base / 3072, k = base % 3072;
    const float4 va = *(const float4*)(FW + base);
    const float4 vb = *(const float4*)(FW + base + 4);
    const float xs[8] = {va.x, va.y, va.z, va.w, vb.x, vb.y, vb.z, vb.w};
    union { unsigned short s[8]; bf16x8 v; } hi, lo;
    #pragma unroll
    for (int j = 0; j < 8; j++){
      hi.s[j] = f2bf_rne(xs[j]);
      lo.s[j] = f2bf_rne(xs[j] - bf2f(hi.s[j]));
    }
    *(bf16x8*)(fw2 + (size_t)o * 6144 + k) = hi.v;
    *(bf16x8*)(fw2 + (size_t)o * 6144 + 3072 + k) = lo.v;
  }
}

// ---------------- pointnet GEMM: direct-global B, o-split across waves (r3-verified) -----
// 512-thread blocks, 8 waves = 2 o-halves x 4 n-groups. Each wave: (C/2) o x 48 n.
// o-split keeps acc at 48 VGPR (C=128) -> no spill (r2 post-mortem); duplicate B loads
// between the two o-halves hit L1. 2-deep register double buffer prefetches the next
// K-step's 24 B loads under the current step's MFMAs (fully unrolled -> static indices).
#define SROW 196
template<int C>
__device__ __forceinline__ void pn_body(
    int nchunk, int b,
    const float* __restrict__ xyz, const float* __restrict__ feats,
    const unsigned short* __restrict__ Wb, float* __restrict__ part,
    float* yb /* 2 * 16*SROW floats LDS */){
  constexpr int KPAD = C + 32;
  constexpr int NFK  = C / 32;      // K-steps over feats
  constexpr int MTH  = C / 32;      // m-tiles per o-half ((C/2)/16)
  const int tid  = threadIdx.x;     // 0..511
  const int lane = tid & 63, w = tid >> 6;
  const int wo = w >> 2, wn = w & 3;       // o-half, n-group
  const int g = lane >> 4, l16 = lane & 15;
  const int o_off = wo * (C / 2);
  const int nbase = nchunk * 192;

  int nn[3], pp[3];
  #pragma unroll
  for (int t = 0; t < 3; t++){
    nn[t] = wn * 48 + t * 16 + l16;          // local n in [0,192)
    pp[t] = (nbase + nn[t]) / 12;            // global point index
  }

  f32x4 acc[MTH][3];
  #pragma unroll
  for (int m = 0; m < MTH; m++)
    #pragma unroll
    for (int t = 0; t < 3; t++)
      acc[m][t] = (f32x4){0.f, 0.f, 0.f, 0.f};

  const float* fB = feats + (size_t)b * C * (NPTS * NANG) + nbase;

  // 2-deep register double buffer for B fragments
  float fbuf[2][3][8];
  #pragma unroll
  for (int t = 0; t < 3; t++)
    #pragma unroll
    for (int j = 0; j < 8; j++)
      fbuf[0][t][j] = fB[(size_t)(g * 8 + j) * (NPTS * NANG) + nn[t]];

  #pragma unroll
  for (int ks = 0; ks < NFK; ks++){
    const int cur = ks & 1;
    if (ks + 1 < NFK){
      const int kb = (ks + 1) * 32;
      #pragma unroll
      for (int t = 0; t < 3; t++)
        #pragma unroll
        for (int j = 0; j < 8; j++)
          fbuf[cur ^ 1][t][j] = fB[(size_t)(kb + g * 8 + j) * (NPTS * NANG) + nn[t]];
    }
    const int kb = ks * 32;
    bf16x8 Bf[3];
    #pragma unroll
    for (int t = 0; t < 3; t++) Bf[t] = pack8(fbuf[cur][t]);
    #pragma unroll
    for (int m = 0; m < MTH; m++){
      const bf16x8 Af = *(const bf16x8*)(Wb + (size_t)(o_off + m * 16 + l16) * KPAD + kb + g * 8);
      #pragma unroll
      for (int t = 0; t < 3; t++)
        acc[m][t] = __builtin_amdgcn_mfma_f32_16x16x32_bf16(Af, Bf[t], acc[m][t], 0, 0, 0);
    }
  }

  { // xyz K-step (k = C..C+2 non-zero), register B
    const int kb = C;
    bf16x8 Bf2[3];
    #pragma unroll
    for (int t = 0; t < 3; t++){
      float f[8];
      #pragma unroll
      for (int j = 0; j < 8; j++) f[j] = 0.f;
      if (g == 0){
        #pragma unroll
        for (int j = 0; j < 3; j++)
          f[j] = xyz[(size_t)(b * 3 + j) * NPTS + pp[t]];
      }
      Bf2[t] = pack8(f);
    }
    #pragma unroll
    for (int m = 0; m < MTH; m++){
      const bf16x8 Af = *(const bf16x8*)(Wb + (size_t)(o_off + m * 16 + l16) * KPAD + kb + g * 8);
      #pragma unroll
      for (int t = 0; t < 3; t++)
        acc[m][t] = __builtin_amdgcn_mfma_f32_16x16x32_bf16(Af, Bf2[t], acc[m][t], 0, 0, 0);
    }
  }

  // reduce: per m-tile (per o-half in its own LDS buffer), 16 o x 192 n, max over 16 points
  float* myb = yb + wo * (16 * SROW);
  #pragma unroll
  for (int m = 0; m < MTH; m++){
    __syncthreads();
    #pragma unroll
    for (int t = 0; t < 3; t++)
      #pragma unroll
      for (int r = 0; r < 4; r++)
        myb[(g * 4 + r) * SROW + nn[t]] = acc[m][t][r];
    __syncthreads();
    const int lt = tid & 255;                // local thread within o-half
    if (lt < 192){
      const int o_l = lt / 12, a = lt % 12;
      float mx = -3.4e38f;
      #pragma unroll
      for (int pl = 0; pl < 16; pl++)
        mx = fmaxf(mx, myb[o_l * SROW + pl * 12 + a]);
      part[((size_t)(b * 64 + nchunk) * C + o_off + m * 16 + o_l) * 12 + a] = mx;
    }
  }
}

__global__ __launch_bounds__(512, 4) void pn_both(
    const float* __restrict__ xyz0, const float* __restrict__ feats0,
    const unsigned short* __restrict__ wb0, float* __restrict__ part0,
    const float* __restrict__ xyz1, const float* __restrict__ feats1,
    const unsigned short* __restrict__ wb1, float* __restrict__ part1){
  __shared__ float yb[2 * 16 * SROW];   // 25 KB (two reduce buffers)
  // interleave light (C=64) / heavy (C=128) blocks so CUs get a mix, not a heavy tail
  const int lin   = blockIdx.x + 64 * (blockIdx.y + 16 * blockIdx.z);
  const int which = lin & 1;
  const int rest  = lin >> 1;           // bijective: [0,1024) per which
  const int nchunk = rest & 63, b = rest >> 6;
  if (which == 0) pn_body<64> (nchunk, b, xyz0, feats0, wb0, part0, yb);
  else            pn_body<128>(nchunk, b, xyz1, feats1, wb1, part1, yb);
}

// ---------------- reduce chunks + bias + BN + relu -> xcat (16,192,12) ----------------
__global__ void pn_reduce_bn(const float* __restrict__ part0, const float* __restrict__ part1,
    const float* __restrict__ b0, const float* __restrict__ g0, const float* __restrict__ bb0,
    const float* __restrict__ b1, const float* __restrict__ g1, const float* __restrict__ bb1,
    float* __restrict__ xcat){
  const int ch = blockIdx.x, t = threadIdx.x;
  const int b = t / 12, a = t % 12;
  const float* part; const float *bias, *g, *bb; int o, Cl;
  if (ch < 64){ part = part0; bias = b0; g = g0; bb = bb0; o = ch;      Cl = 64;  }
  else        { part = part1; bias = b1; g = g1; bb = bb1; o = ch - 64; Cl = 128; }
  const float* pp = part + ((size_t)(b * 64) * Cl + o) * 12 + a;
  const size_t kstride = (size_t)Cl * 12;
  float v = pp[0];
  for (int k = 1; k < 64; k++) v = fmaxf(v, pp[(size_t)k * kstride]);
  v += bias[o];
  __shared__ float sbuf[8];
  float m, var;
  block_stats<192>(v, m, var, sbuf);
  float xn = (v - m) * rsqrtf(var + EPSV) * g[o] + bb[o];
  xcat[((size_t)b * 192 + ch) * 12 + a] = fmaxf(xn, 0.f);
}

// ---------------- lin layer + BN (no relu) -> xlin (16,256,12) ----------------
__global__ void lin_bn(const float* __restrict__ xcat, const float* __restrict__ W,
    const float* __restrict__ bias, const float* __restrict__ g, const float* __restrict__ bb,
    float* __restrict__ xlin){
  const int o = blockIdx.x, t = threadIdx.x;
  const int b = t / 12, a = t % 12;
  const float* xr = xcat + (size_t)b * 2304 + a;
  const float* wr = W + (size_t)o * 192;
  float v = bias[o];
  for (int c = 0; c < 192; c++) v = fmaf(wr[c], xr[(size_t)c * 12], v);
  __shared__ float sbuf[8];
  float m, var;
  block_stats<192>(v, m, var, sbuf);
  xlin[((size_t)b * 256 + o) * 12 + a] = (v - m) * rsqrtf(var + EPSV) * g[o] + bb[o];
}

// ---------------- prep: gathered activations Xg [n=960][hi(3072) | lo(3072)] bf16 --------
__global__ void prep_xg(const float* __restrict__ xlin, const int* __restrict__ trace,
                        unsigned short* __restrict__ Xg){
  const int n = blockIdx.x;           // 0..959
  const int b = n / 60, r = n % 60;
  unsigned short* row = Xg + (size_t)n * 6144;
  __shared__ int ta[12];
  if (threadIdx.x < 12) ta[threadIdx.x] = trace[threadIdx.x * 60 + r];
  __syncthreads();
  for (int i = threadIdx.x; i < 3072; i += 256){
    const int c = i / 12, a = i % 12;
    const float x = xlin[((size_t)b * 256 + c) * 12 + ta[a]];
    const unsigned short hi = f2bf_rne(x);
    const unsigned short lo = f2bf_rne(x - bf2f(hi));
    row[i] = hi;
    row[3072 + i] = lo;
  }
}

// ---------------- feat GEMM: LDS-staged MFMA, XOR-swizzled chunks ----------------
__global__ __launch_bounds__(256) void feat_mfma(
    const unsigned short* __restrict__ Wb2, const unsigned short* __restrict__ Xg,
    float* __restrict__ fraw){
  const int nblk = blockIdx.x, mblk = blockIdx.y, seg = blockIdx.z;
  const int tid = threadIdx.x;
  const int lane = tid & 63, wave = tid >> 6;
  const int g = lane >> 4, l16 = lane & 15;
  const int kA = (seg == 1) ? 3072 : 0;
  const int kB = (seg == 2) ? 3072 : 0;
  const int sw = l16 & 7;
  const int wm = wave >> 1, wn = wave & 1;

  __shared__ unsigned short As[2][64 * 64];
  __shared__ unsigned short Bs[2][64 * 64];

  int rowj[2], colj[2], ldsoff[2];
  #pragma unroll
  for (int j = 0; j < 2; j++){
    const int idx = j * 256 + wave * 64 + lane;
    rowj[j]   = idx >> 3;
    colj[j]   = ((idx & 7) ^ (rowj[j] & 7)) * 8;
    ldsoff[j] = (j * 256 + wave * 64) * 8;
  }
  const unsigned short* Agb = Wb2 + (size_t)mblk * 64 * 6144 + kA;
  const unsigned short* Bgb = Xg  + (size_t)nblk * 64 * 6144 + kB;

  f32x4 acc[2][2];
  #pragma unroll
  for (int i = 0; i < 2; i++)
    #pragma unroll
    for (int j = 0; j < 2; j++)
      acc[i][j] = (f32x4){0.f, 0.f, 0.f, 0.f};

  #pragma unroll
  for (int j = 0; j < 2; j++){
    stage16(Agb + (size_t)rowj[j] * 6144 + colj[j], &As[0][ldsoff[j]]);
    stage16(Bgb + (size_t)rowj[j] * 6144 + colj[j], &Bs[0][ldsoff[j]]);
  }
  __syncthreads();

  for (int kc = 0; kc < 3072; kc += 64){
    const int buf = (kc >> 6) & 1;
    if (kc + 64 < 3072){
      const int kn = kc + 64;
      #pragma unroll
      for (int j = 0; j < 2; j++){
        stage16(Agb + (size_t)rowj[j] * 6144 + kn + colj[j], &As[buf ^ 1][ldsoff[j]]);
        stage16(Bgb + (size_t)rowj[j] * 6144 + kn + colj[j], &Bs[buf ^ 1][ldsoff[j]]);
      }
    }
    #pragma unroll
    for (int kc2 = 0; kc2 < 64; kc2 += 32){
      const int c0 = kc2 >> 3;
      bf16x8 af[2], bfr[2];
      #pragma unroll
      for (int i = 0; i < 2; i++)
        af[i]  = *(const bf16x8*)&As[buf][(wm * 32 + i * 16 + l16) * 64 + ((c0 + g) ^ sw) * 8];
      #pragma unroll
      for (int i = 0; i < 2; i++)
        bfr[i] = *(const bf16x8*)&Bs[buf][(wn * 32 + i * 16 + l16) * 64 + ((c0 + g) ^ sw) * 8];
      #pragma unroll
      for (int i = 0; i < 2; i++)
        #pragma unroll
        for (int j = 0; j < 2; j++)
          acc[i][j] = __builtin_amdgcn_mfma_f32_16x16x32_bf16(af[i], bfr[j], acc[i][j], 0, 0, 0);
    }
    __syncthreads();
  }

  float* base = fraw + (size_t)seg * (512 * 960);
  #pragma unroll
  for (int i = 0; i < 2; i++)
    #pragma unroll
    for (int j = 0; j < 2; j++){
      const int n = nblk * 64 + wn * 32 + j * 16 + l16;
      #pragma unroll
      for (int q = 0; q < 4; q++){
        const int m = mblk * 64 + wm * 32 + i * 16 + g * 4 + q;
        base[(size_t)m * 960 + n] = acc[i][j][q];
      }
    }
}

// ---------------- feat: sum 3 segs + bias + BN + relu + per-b max over r ----------------
__global__ void feat_bn(const float* __restrict__ fraw, const float* __restrict__ bias,
    const float* __restrict__ g, const float* __restrict__ bb,
    float* __restrict__ xf, float* __restrict__ xm){
  const int o = blockIdx.x, t = threadIdx.x;
  const int b = t / 60, r = t % 60;
  const size_t SS = (size_t)512 * 960;
  const size_t in = (size_t)o * 960 + t;
  float v = fraw[in] + fraw[SS + in] + fraw[2 * SS + in] + bias[o];
  __shared__ float sbuf[32];
  float m, var;
  block_stats<960>(v, m, var, sbuf);
  const float xn = fmaxf((v - m) * rsqrtf(var + EPSV) * g[o] + bb[o], 0.f);
  xf[((size_t)b * 512 + o) * 60 + r] = xn;
  __shared__ float red[960];
  red[t] = xn;
  __syncthreads();
  if (r == 0){
    float mx = red[t];
    for (int k = 1; k < 60; k++) mx = fmaxf(mx, red[t + k]);
    xm[(size_t)b * 512 + o] = mx;
  }
}

// ---------------- branch GEMMs fused (reg_W1 & att_W1), K split 8; + out_head1 -----------
__global__ __launch_bounds__(256) void brgemm_oh1(const float* __restrict__ xf,
    const float* __restrict__ Wr, const float* __restrict__ Wa,
    float* __restrict__ brp,
    const float* __restrict__ xm, const float* __restrict__ oW1,
    const float* __restrict__ ob1, const float* __restrict__ og,
    const float* __restrict__ obb, float* __restrict__ o_act){
  const int z = blockIdx.z;
  if (z == 16){
    const int q = blockIdx.y * 4 + blockIdx.x;
    if (q >= 32) return;
    const int t = threadIdx.x;
    const int b = t & 15, j = t >> 4;
    const int oc = q * 16 + j;
    float acc = ob1[oc];
    const float* wr = oW1 + (size_t)oc * 512;
    const float* xr = xm + (size_t)b * 512;
    for (int c = 0; c < 512; c++) acc = fmaf(wr[c], xr[c], acc);
    float s = acc, s2 = acc * acc;
    #pragma unroll
    for (int off = 8; off; off >>= 1){
      s  += __shfl_xor(s,  off, 16);
      s2 += __shfl_xor(s2, off, 16);
    }
    const float m = s * (1.f / 16.f);
    const float var = s2 * (1.f / 16.f) - m * m;
    o_act[(size_t)b * 512 + oc] = fmaxf((acc - m) * rsqrtf(var + EPSV) * og[oc] + obb[oc], 0.f);
    return;
  }
  const int og_ = blockIdx.x, b = blockIdx.y;
  const int br = z >> 3, ks = z & 7;
  const float* W = br ? Wa : Wr;
  const int lane = threadIdx.x & 63, wave = threadIdx.x >> 6;
  const int obase = og_ * 32 + wave * 8;
  const int rr = lane < 60 ? lane : 0;
  const float* xb = xf + ((size_t)b * 512 + ks * 64) * 60 + rr;
  const float* wr = W + (size_t)obase * 512 + ks * 64;

  float acc[8];
  #pragma unroll
  for (int i = 0; i < 8; i++) acc[i] = 0.f;

  float cur[4], nxt[4];
  #pragma unroll
  for (int j = 0; j < 4; j++) cur[j] = xb[(size_t)j * 60];

  for (int c0 = 0; c0 < 64; c0 += 4){
    #pragma unroll
    for (int j = 0; j < 4; j++){
      int cc = c0 + 4 + j; if (cc > 63) cc = 63;
      nxt[j] = xb[(size_t)cc * 60];
    }
    #pragma unroll
    for (int j = 0; j < 4; j++)
      #pragma unroll
      for (int i = 0; i < 8; i++)
        acc[i] = fmaf(wr[(size_t)i * 512 + c0 + j], cur[j], acc[i]);
    #pragma unroll
    for (int j = 0; j < 4; j++) cur[j] = nxt[j];
  }

  if (lane < 60){
    #pragma unroll
    for (int i = 0; i < 8; i++)
      brp[(((size_t)z * NBATCH + b) * 128 + obase + i) * 60 + lane] = acc[i];
  }
}

// ---------------- branch: sum 8 K-slabs + bias + BN + relu ----------------
__global__ void br_bn(const float* __restrict__ brp,
    const float* __restrict__ biasR, const float* __restrict__ gR, const float* __restrict__ bbR,
    const float* __restrict__ biasA, const float* __restrict__ gA, const float* __restrict__ bbA,
    float* __restrict__ hact, float* __restrict__ aact){
  const int o = blockIdx.x, br = blockIdx.y, t = threadIdx.x;
  const int b = t / 60, r = t % 60;
  const float* bias = br ? biasA : biasR;
  const float* g    = br ? gA    : gR;
  const float* bb   = br ? bbA   : bbR;
  float v = bias[o];
  #pragma unroll
  for (int ks = 0; ks < 8; ks++)
    v += brp[((((size_t)br * 8 + ks) * NBATCH + b) * 128 + o) * 60 + r];
  __shared__ float sbuf[32];
  float m, var;
  block_stats<960>(v, m, var, sbuf);
  float* outp = br ? aact : hact;
  outp[((size_t)b * 128 + o) * 60 + r] =
      fmaxf((v - m) * rsqrtf(var + EPSV) * g[o] + bb[o], 0.f);
}

// ---------------- heads: reg2_geom (y=0), att2_softmax (y=1), out_head2 (y=2) ------------
__global__ void heads(
    const float* __restrict__ h, const float* __restrict__ rW2,
    const float* __restrict__ rb2, const float* __restrict__ anchors,
    const float* __restrict__ a, const float* __restrict__ aW2, const float* __restrict__ ab2,
    const float* __restrict__ o_act, const float* __restrict__ oW2,
    const float* __restrict__ ob2, float* __restrict__ out){
  const int b = blockIdx.x, sel = blockIdx.y, t = threadIdx.x;
  if (sel == 0){
    if (t >= 64) return;
    const int r = t < 60 ? t : 59;
    float res[7];
    #pragma unroll
    for (int j = 0; j < 7; j++) res[j] = rb2[j];
    for (int c = 0; c < 128; c++){
      const float hv = h[((size_t)b * 128 + c) * 60 + r];
      #pragma unroll
      for (int j = 0; j < 7; j++) res[j] = fmaf(rW2[j * 128 + c], hv, res[j]);
    }
    if (t >= 60) return;
    const float n = sqrtf(res[0]*res[0] + res[1]*res[1] + res[2]*res[2]);
    const float invn = 1.f / n;
    const float Nv = (1.f / (1.f + expf(-res[3])) - 0.5f) * 3.14159265358979323846f / 5.f;
    const float v0 = res[0]*invn*Nv, v1 = res[1]*invn*Nv, v2 = res[2]*invn*Nv;
    const float th = sqrtf(v0*v0 + v1*v1 + v2*v2);
    const float invt = th < 1e-8f ? 1.f : 1.f / th;
    const float k0 = v0*invt, k1 = v1*invt, k2 = v2*invt;
    const float s = sinf(th), cc = 1.f - cosf(th);
    const float K[9] = {0.f, -k2, k1,  k2, 0.f, -k0,  -k1, k0, 0.f};
    float K2[9];
    #pragma unroll
    for (int ii = 0; ii < 3; ii++)
      #pragma unroll
      for (int jj = 0; jj < 3; jj++)
        K2[ii*3+jj] = K[ii*3+0]*K[0*3+jj] + K[ii*3+1]*K[1*3+jj] + K[ii*3+2]*K[2*3+jj];
    float R[9];
    #pragma unroll
    for (int ii = 0; ii < 3; ii++)
      #pragma unroll
      for (int jj = 0; jj < 3; jj++)
        R[ii*3+jj] = (ii == jj ? 1.f : 0.f) + s * K[ii*3+jj] + cc * K2[ii*3+jj];
    const float* A = anchors + (size_t)t * 9;
    #pragma unroll
    for (int ii = 0; ii < 3; ii++)
      #pragma unroll
      for (int kk = 0; kk < 3; kk++){
        const float pv = A[ii*3+0]*R[0*3+kk] + A[ii*3+1]*R[1*3+kk] + A[ii*3+2]*R[2*3+kk];
        out[OUT_PRED + ((size_t)b * 60 + t) * 9 + ii * 3 + kk] = pv;
      }
    #pragma unroll
    for (int k = 0; k < 3; k++)
      out[OUT_REST + ((size_t)b * 60 + t) * 3 + k] = res[4 + k];
  } else if (sel == 1){
    if (t >= 64) return;
    const int r = t < 60 ? t : 59;
    float acc = ab2[0];
    for (int c = 0; c < 128; c++)
      acc = fmaf(aW2[c], a[((size_t)b * 128 + c) * 60 + r], acc);
    const float l = t < 60 ? acc : -INFINITY;
    float mx = l;
    #pragma unroll
    for (int off = 32; off; off >>= 1) mx = fmaxf(mx, __shfl_xor(mx, off, 64));
    const float e = t < 60 ? expf(l - mx) : 0.f;
    float ssum = e;
    #pragma unroll
    for (int off = 32; off; off >>= 1) ssum += __shfl_xor(ssum, off, 64);
    if (t < 60) out[OUT_ATTN + (size_t)b * 60 + t] = e / ssum;
  } else {
    const float* wr = oW2 + (size_t)t * 512;
    const float* xr = o_act + (size_t)b * 512;
    float acc = ob2[t];
    for (int c = 0; c < 512; c++) acc = fmaf(wr[c], xr[c], acc);
    out[OUT_XOUT + (size_t)b * 256 + t] = acc;
  }
}

// ---------------- launch ----------------
extern "C" void kernel_launch(void* const* d_in, const int* in_sizes, int n_in,
                              void* d_out, int out_size, void* d_ws, size_t ws_size,
                              hipStream_t stream){
  const float* xyz0    = (const float*)d_in[0];
  const float* feats0  = (const float*)d_in[1];
  const float* xyz1    = (const float*)d_in[2];
  const float* feats1  = (const float*)d_in[3];
  const int*   trace   = (const int*)  d_in[4];
  const float* anchors = (const float*)d_in[5];
  const float* pn0_W  = (const float*)d_in[6];
  const float* pn0_b  = (const float*)d_in[7];
  const float* pn0_g  = (const float*)d_in[8];
  const float* pn0_bb = (const float*)d_in[9];
  const float* pn1_W  = (const float*)d_in[10];
  const float* pn1_b  = (const float*)d_in[11];
  const float* pn1_g  = (const float*)d_in[12];
  const float* pn1_bb = (const float*)d_in[13];
  const float* lin_W  = (const float*)d_in[14];
  const float* lin_b  = (const float*)d_in[15];
  const float* lin_g  = (const float*)d_in[16];
  const float* lin_bb = (const float*)d_in[17];
  const float* feat_W  = (const float*)d_in[18];
  const float* feat_b  = (const float*)d_in[19];
  const float* feat_g  = (const float*)d_in[20];
  const float* feat_bb = (const float*)d_in[21];
  const float* att_W1 = (const float*)d_in[22];
  const float* att_b1 = (const float*)d_in[23];
  const float* att_g  = (const float*)d_in[24];
  const float* att_bb = (const float*)d_in[25];
  const float* att_W2 = (const float*)d_in[26];
  const float* att_b2 = (const float*)d_in[27];
  const float* reg_W1 = (const float*)d_in[28];
  const float* reg_b1 = (const float*)d_in[29];
  const float* reg_g  = (const float*)d_in[30];
  const float* reg_bb = (const float*)d_in[31];
  const float* reg_W2 = (const float*)d_in[32];
  const float* reg_b2 = (const float*)d_in[33];
  const float* out_W1 = (const float*)d_in[34];
  const float* out_b1 = (const float*)d_in[35];
  const float* out_g  = (const float*)d_in[36];
  const float* out_bb = (const float*)d_in[37];
  const float* out_W2 = (const float*)d_in[38];
  const float* out_b2 = (const float*)d_in[39];

  float* ws  = (float*)d_ws;
  float* out = (float*)d_out;
  unsigned short* wb0 = (unsigned short*)(ws + WB0_OFF);
  unsigned short* wb1 = (unsigned short*)(ws + WB1_OFF);
  unsigned short* fw  = (unsigned short*)(ws + FEATW_OFF);
  unsigned short* xg  = (unsigned short*)(ws + XG_OFF);

  // 1. all weight prep in one launch (featw vectorized)
  prep_all<<<872, 256, 0, stream>>>(pn0_W, pn1_W, feat_W, wb0, wb1, fw);

  // 2. both pointnets: direct-global B, o-split waves, register-dbuf prefetch (r3-verified)
  pn_both<<<dim3(64, 16, 2), 512, 0, stream>>>(xyz0, feats0, wb0, ws + PART0_OFF,
                                               xyz1, feats1, wb1, ws + PART1_OFF);

  // 3. reduce + BN + relu -> concat
  pn_reduce_bn<<<192, 192, 0, stream>>>(ws + PART0_OFF, ws + PART1_OFF,
      pn0_b, pn0_g, pn0_bb, pn1_b, pn1_g, pn1_bb, ws + XCAT_OFF);

  // 4. lin + BN
  lin_bn<<<256, 192, 0, stream>>>(ws + XCAT_OFF, lin_W, lin_b, lin_g, lin_bb, ws + XLIN_OFF);

  // 5. gathered activations hi/lo
  prep_xg<<<960, 256, 0, stream>>>(ws + XLIN_OFF, trace, xg);

  // 6. feat GEMM via LDS-staged MFMA (3 segments)
  feat_mfma<<<dim3(15, 8, 3), 256, 0, stream>>>(fw, xg, ws + FRAW_OFF);

  // 7. sum segs + BN + relu + per-b max
  feat_bn<<<512, 960, 0, stream>>>(ws + FRAW_OFF, feat_b, feat_g, feat_bb,
                                   ws + XF_OFF, ws + XM_OFF);

  // 8. branch GEMMs (K split 8) + out_head1 merged as z=16
  brgemm_oh1<<<dim3(4, 16, 17), 256, 0, stream>>>(ws + XF_OFF, reg_W1, att_W1, ws + BRP_OFF,
      ws + XM_OFF, out_W1, out_b1, out_g, out_bb, ws + OACT_OFF);

  // 9. branch BN
  br_bn<<<dim3(128, 2), 960, 0, stream>>>(ws + BRP_OFF,
      reg_b1, reg_g, reg_bb, att_b1, att_g, att_bb,
      ws + HACT_OFF, ws + AACT_OFF);

  // 10. heads
  heads<<<dim3(16, 3), 256, 0, stream>>>(ws + HACT_OFF, reg_W2, reg_b2, anchors,
      ws + AACT_OFF, att_W2, att_b2, ws + OACT_OFF, out_W2, out_b2, out);
}